// Round 1
// baseline (2071.127 us; speedup 1.0000x reference)
//
#include <hip/hip_runtime.h>
#include <math.h>

#define TL 128        // text length (m)
#define IL 100        // image length (n)
#define ILP 104       // n padded to multiple of 4
#define DIM 768
#define NSEQ 228
#define KT 32         // K tile
#define XLD 132       // LDS leading dim for X tile (128+4 pad)
#define YLD 104       // LDS leading dim for Y tile
#define NTHREADS 832  // 13 waves; thread grid 32 (m-groups) x 26 (n-groups)
#define NWAVES 13
#define ITERS 50

typedef float v2f __attribute__((ext_vector_type(2)));

__global__ void __launch_bounds__(NTHREADS, 4)
WRA_ot_kernel(const float* __restrict__ seq,
              const int* __restrict__ txt_pad,
              const int* __restrict__ img_pad,
              const int* __restrict__ is_correct,
              float* __restrict__ out, int nblocks)
{
    __shared__ __align__(16) float Xt[KT * XLD];
    __shared__ __align__(16) float Yt[KT * YLD];
    __shared__ __align__(16) float xm[TL];    // txt pad mask * 1e4
    __shared__ __align__(16) float ym[ILP];   // img pad mask * 1e4 (pad rows -> 1e4)
    __shared__ __align__(16) float inx[TL];   // sum sq -> inv norm (text)
    __shared__ __align__(16) float iny[ILP];  // sum sq -> inv norm (img)
    __shared__ __align__(16) float sig[TL];   // sigma
    __shared__ __align__(16) float wp[NWAVES * TL]; // per-wave partials for s[m]
    __shared__ float red[NWAVES];
    __shared__ int cnt[2];

    const int t  = threadIdx.x;
    const int b  = blockIdx.x;
    const int mg = t & 31;   // m-group: m in [4mg, 4mg+4)
    const int ng = t >> 5;   // n-group: n in [4ng, 4ng+4), 0..25 (24.. partially fake)
    const int wv = t >> 6;   // wave id 0..12

    // ---- masks & lengths ----
    if (t < 2) cnt[t] = 0;
    __syncthreads();
    if (t < TL) {
        int p = txt_pad[b * TL + t] ? 1 : 0;
        xm[t] = p ? 1e4f : 0.0f;
        if (p) atomicAdd(&cnt[0], 1);
    } else if (t < TL + IL) {
        int p = img_pad[b * IL + (t - TL)] ? 1 : 0;
        ym[t - TL] = p ? 1e4f : 0.0f;
        if (p) atomicAdd(&cnt[1], 1);
    } else if (t < TL + ILP) {
        ym[t - TL] = 1e4f;   // fake rows n=100..103
    }

    // ---- GEMM phase: D[m,n] = sum_k X[m,k] Y[n,k]; norms accumulated inline ----
    const float* Xg = seq + (size_t)b * NSEQ * DIM;       // text rows 0..127
    const float* Yg = Xg + (size_t)TL * DIM;              // img rows 0..99

    v2f acc[4][4];   // [j = n idx][i = m idx]
    v2f sx2[4], sy2[4];
#pragma unroll
    for (int j = 0; j < 4; j++) {
        sx2[j].x = 0.f; sx2[j].y = 0.f;
        sy2[j].x = 0.f; sy2[j].y = 0.f;
#pragma unroll
        for (int i = 0; i < 4; i++) { acc[j][i].x = 0.f; acc[j][i].y = 0.f; }
    }
    const bool do_sx = (ng == 0);
    const bool do_sy = (mg == 0);

    for (int kt0 = 0; kt0 < DIM; kt0 += KT) {
        __syncthreads();
        for (int f = t; f < (TL * KT / 4); f += NTHREADS) {   // 1024 float4
            int row = f >> 3, kc = (f & 7) << 2;
            float4 v = *(const float4*)(Xg + row * DIM + kt0 + kc);
            Xt[(kc + 0) * XLD + row] = v.x;
            Xt[(kc + 1) * XLD + row] = v.y;
            Xt[(kc + 2) * XLD + row] = v.z;
            Xt[(kc + 3) * XLD + row] = v.w;
        }
        for (int f = t; f < (IL * KT / 4); f += NTHREADS) {   // 800 float4
            int row = f >> 3, kc = (f & 7) << 2;
            float4 v = *(const float4*)(Yg + row * DIM + kt0 + kc);
            Yt[(kc + 0) * YLD + row] = v.x;
            Yt[(kc + 1) * YLD + row] = v.y;
            Yt[(kc + 2) * YLD + row] = v.z;
            Yt[(kc + 3) * YLD + row] = v.w;
        }
        __syncthreads();
#pragma unroll
        for (int kk = 0; kk < KT; kk += 2) {
            float4 xa = *(const float4*)&Xt[kk * XLD + 4 * mg];
            float4 xb = *(const float4*)&Xt[(kk + 1) * XLD + 4 * mg];
            float4 ya = *(const float4*)&Yt[kk * YLD + 4 * ng];
            float4 yb = *(const float4*)&Yt[(kk + 1) * YLD + 4 * ng];
            v2f px[4] = { {xa.x, xb.x}, {xa.y, xb.y}, {xa.z, xb.z}, {xa.w, xb.w} };
            v2f py[4] = { {ya.x, yb.x}, {ya.y, yb.y}, {ya.z, yb.z}, {ya.w, yb.w} };
#pragma unroll
            for (int j = 0; j < 4; j++)
#pragma unroll
                for (int i = 0; i < 4; i++)
                    acc[j][i] += px[i] * py[j];
            if (do_sx) {
#pragma unroll
                for (int i = 0; i < 4; i++) sx2[i] += px[i] * px[i];
            }
            if (do_sy) {
#pragma unroll
                for (int j = 0; j < 4; j++) sy2[j] += py[j] * py[j];
            }
        }
    }

    if (do_sx) {
#pragma unroll
        for (int i = 0; i < 4; i++) inx[4 * mg + i] = sx2[i].x + sx2[i].y;
    }
    if (do_sy) {
#pragma unroll
        for (int j = 0; j < 4; j++) iny[4 * ng + j] = sy2[j].x + sy2[j].y;
    }
    __syncthreads();
    if (t < TL) {
        inx[t] = 1.0f / fmaxf(sqrtf(inx[t]), 1e-5f);
    } else if (t < TL + ILP) {
        iny[t - TL] = 1.0f / fmaxf(sqrtf(iny[t - TL]), 1e-5f);
    }
    __syncthreads();

    const float xlen = (float)(TL - cnt[0]);
    const float ylen = (float)(IL - cnt[1]);

    float4 f4;
    float rx[4], ry[4], xmv[4], ymv[4];
    f4 = *(const float4*)&inx[4 * mg]; rx[0]=f4.x; rx[1]=f4.y; rx[2]=f4.z; rx[3]=f4.w;
    f4 = *(const float4*)&iny[4 * ng]; ry[0]=f4.x; ry[1]=f4.y; ry[2]=f4.z; ry[3]=f4.w;
    f4 = *(const float4*)&xm[4 * mg];  xmv[0]=f4.x; xmv[1]=f4.y; xmv[2]=f4.z; xmv[3]=f4.w;
    f4 = *(const float4*)&ym[4 * ng];  ymv[0]=f4.x; ymv[1]=f4.y; ymv[2]=f4.z; ymv[3]=f4.w;

    // cc = masked cost, aa = masked exp(-2C), qq = running Q (Q_1 = A)
    float cc[4][4], aa[4][4], qq[4][4];
#pragma unroll
    for (int j = 0; j < 4; j++)
#pragma unroll
        for (int i = 0; i < 4; i++) {
            float d = acc[j][i].x + acc[j][i].y;
            bool pad = (xmv[i] > 0.0f) || (ymv[j] > 0.0f);
            float c = pad ? 0.0f : (1.0f - d * rx[i] * ry[j]);
            float a = pad ? 0.0f : expf(-2.0f * c);
            cc[j][i] = c; aa[j][i] = a; qq[j][i] = a;
        }

    // sigma_0
    if (t < TL) sig[t] = (xm[t] > 0.0f) ? 0.0f : (1.0f / xlen);
    __syncthreads();

    float ss[4];
    f4 = *(const float4*)&sig[4 * mg]; ss[0]=f4.x; ss[1]=f4.y; ss[2]=f4.z; ss[3]=f4.w;

    float dl[4];
    for (int it = 0; it < ITERS; ++it) {
        // qs[n] = sum_m Q sigma ; butterfly over the 32 m-groups (contiguous half-wave)
#pragma unroll
        for (int j = 0; j < 4; j++) {
            float p = qq[j][0]*ss[0] + qq[j][1]*ss[1] + qq[j][2]*ss[2] + qq[j][3]*ss[3];
            p += __shfl_xor(p, 1);
            p += __shfl_xor(p, 2);
            p += __shfl_xor(p, 4);
            p += __shfl_xor(p, 8);
            p += __shfl_xor(p, 16);
            dl[j] = __builtin_amdgcn_rcpf(ylen * p + ymv[j]);
        }
        // s[m] = sum_n delta Q : in-thread (4 n) + cross-half (xor 32) + 13-wave LDS combine
        float sp[4];
#pragma unroll
        for (int i = 0; i < 4; i++) {
            float s = dl[0]*qq[0][i] + dl[1]*qq[1][i] + dl[2]*qq[2][i] + dl[3]*qq[3][i];
            s += __shfl_xor(s, 32);
            sp[i] = s;
        }
        if ((t & 63) < 32) {
            *(float4*)&wp[wv * TL + 4 * mg] = make_float4(sp[0], sp[1], sp[2], sp[3]);
        }
        __syncthreads();
        if (t < TL) {
            float s = 0.0f;
#pragma unroll
            for (int w = 0; w < NWAVES; w++) s += wp[w * TL + t];
            sig[t] = __builtin_amdgcn_rcpf(xlen * s + xm[t]);
        }
        __syncthreads();
        f4 = *(const float4*)&sig[4 * mg]; ss[0]=f4.x; ss[1]=f4.y; ss[2]=f4.z; ss[3]=f4.w;
        if (it < ITERS - 1) {
#pragma unroll
            for (int j = 0; j < 4; j++) {
                float dj = dl[j];
#pragma unroll
                for (int i = 0; i < 4; i++)
                    qq[j][i] = (qq[j][i] * aa[j][i]) * (dj * ss[i]);
            }
        }
    }

    // ot = sum C^T (.) T_50, T_50 = delta (x) Q_50 (.) sigma
    float local = 0.0f;
#pragma unroll
    for (int j = 0; j < 4; j++)
#pragma unroll
        for (int i = 0; i < 4; i++)
            local += cc[j][i] * qq[j][i] * (dl[j] * ss[i]);

    local += __shfl_xor(local, 1);
    local += __shfl_xor(local, 2);
    local += __shfl_xor(local, 4);
    local += __shfl_xor(local, 8);
    local += __shfl_xor(local, 16);
    local += __shfl_xor(local, 32);
    if ((t & 63) == 0) red[wv] = local;
    __syncthreads();
    if (t == 0) {
        float tot = 0.0f;
#pragma unroll
        for (int w = 0; w < NWAVES; w++) tot += red[w];
        float sgn = (is_correct[b] == 1) ? 1.0f : -1.0f;
        atomicAdd(out, sgn * tot / (float)nblocks);
    }
}

extern "C" void kernel_launch(void* const* d_in, const int* in_sizes, int n_in,
                              void* d_out, int out_size, void* d_ws, size_t ws_size,
                              hipStream_t stream) {
    const float* seq     = (const float*)d_in[0];
    // d_in[1] = input_ids (unused), d_in[2] = image_feat (unused by reference math)
    const int* txt_pad   = (const int*)d_in[3];
    const int* img_pad   = (const int*)d_in[4];
    const int* is_corr   = (const int*)d_in[5];
    float* out = (float*)d_out;
    const int B = in_sizes[5];

    hipMemsetAsync(out, 0, sizeof(float), stream);
    WRA_ot_kernel<<<B, NTHREADS, 0, stream>>>(seq, txt_pad, img_pad, is_corr, out, B);
}